// Round 3
// baseline (218.589 us; speedup 1.0000x reference)
//
#include <hip/hip_runtime.h>

// FastAttention (Performer-style, causal), fp32, MI355X.
// B=2, S=1024, H=8, DEPTH=64, NFEAT=64, D_MODEL=512.
// Strategy: every matmul has a wave-uniform operand -> scalar (s_load) loads,
// per-lane operand held in VGPRs (lane = row). No LDS in hot loops.

#define BB 2
#define SS 1024
#define HH 8
#define DD 64
#define FF 64
#define DM 512
#define NCH 16   // chunks of 64 along S

// dst = dot(X[0..63] (regs), ptr[0..63] (uniform row))
#define DOTROW64(dst, X, ptr) do { \
  const float4* _p4 = (const float4*)(ptr); \
  float _p0=0.f,_p1=0.f,_p2=0.f,_p3=0.f; \
  _Pragma("unroll") \
  for (int _j = 0; _j < 16; _j++) { float4 _t = _p4[_j]; \
    _p0 += X[4*_j]   * _t.x; _p1 += X[4*_j+1] * _t.y; \
    _p2 += X[4*_j+2] * _t.z; _p3 += X[4*_j+3] * _t.w; } \
  dst = (_p0+_p1)+(_p2+_p3); \
} while(0)

// ACC[0..63] += a * ptr[0..63] (uniform row)
#define AXPYROW64(ACC, a, ptr) do { \
  const float4* _p4 = (const float4*)(ptr); \
  _Pragma("unroll") \
  for (int _j = 0; _j < 16; _j++) { float4 _t = _p4[_j]; \
    ACC[4*_j]   += (a)*_t.x; ACC[4*_j+1] += (a)*_t.y; \
    ACC[4*_j+2] += (a)*_t.z; ACC[4*_j+3] += (a)*_t.w; } \
} while(0)

// load 64 floats (per-lane address) into register array
#define LOADROW64(R, ptr) do { \
  const float4* _p4 = (const float4*)(ptr); \
  _Pragma("unroll") \
  for (int _j = 0; _j < 16; _j++) { float4 _t = _p4[_j]; \
    R[4*_j]=_t.x; R[4*_j+1]=_t.y; R[4*_j+2]=_t.z; R[4*_j+3]=_t.w; } \
} while(0)

// ---------------- Kernel A: projection + feature map ----------------
// grid = 16 bh * 16 stiles * 3 tasks = 768 blocks, 256 threads.
// lane = row (64 rows per tile); wave = 16-output-column group.
__global__ __launch_bounds__(256) void kproj(
    const float* __restrict__ q_in, const float* __restrict__ k_in,
    const float* __restrict__ v_in,
    const float* __restrict__ Wq, const float* __restrict__ bq,
    const float* __restrict__ Wk, const float* __restrict__ bk,
    const float* __restrict__ Wv, const float* __restrict__ bv,
    const float* __restrict__ orf_q, const float* __restrict__ orf_k,
    float* __restrict__ PHI_Q, float* __restrict__ PHI_K, float* __restrict__ VP)
{
    __shared__ float prt[64*66];   // [row][col] stride 66, float2 access (2-way = free)

    const int tid = threadIdx.x;
    const int l = tid & 63;
    const int w = __builtin_amdgcn_readfirstlane(tid >> 6);
    const int bid = blockIdx.x;
    const int task = bid % 3;
    const int tmp = bid / 3;
    const int stile = tmp & 15;
    const int bh = tmp >> 4;
    const int b = bh >> 3, h = bh & 7;
    const int s = stile*64 + l;

    const float* X  = (task==0) ? q_in : (task==1) ? k_in : v_in;
    const float* W  = (task==0) ? Wq   : (task==1) ? Wk   : Wv;
    const float* bw = (task==0) ? bq   : (task==1) ? bk   : bv;

    // x row -> regs
    float xr[64];
    LOADROW64(xr, X + ((size_t)(b*SS + s))*DM + h*DD);

    // proj: acc[ci] = bias[c] + dot(xr, W[c][:])
    float acc[16];
    #pragma unroll
    for (int ci = 0; ci < 16; ci++) {
        const int c = w*16 + ci;
        float d0; DOTROW64(d0, xr, W + (size_t)c*64);
        acc[ci] = bw[c] + d0;
    }

    if (task == 2) {
        float4* op = (float4*)(VP + ((size_t)bh*SS + s)*DD + w*16);
        #pragma unroll
        for (int j = 0; j < 4; j++)
            op[j] = make_float4(acc[4*j], acc[4*j+1], acc[4*j+2], acc[4*j+3]);
        return; // block-uniform
    }

    // exchange 16-col segments -> full 64 proj row per lane
    #pragma unroll
    for (int m = 0; m < 8; m++)
        *(float2*)&prt[l*66 + w*16 + 2*m] = make_float2(acc[2*m], acc[2*m+1]);
    __syncthreads();
    float pf[64];
    #pragma unroll
    for (int m = 0; m < 32; m++) {
        float2 t = *(float2*)&prt[l*66 + 2*m];
        pf[2*m] = t.x; pf[2*m+1] = t.y;
    }

    const float* ORF = (task==0) ? orf_q : orf_k;
    float* PHI = (task==0) ? PHI_Q : PHI_K;
    const float norm = 0.35355339059327373f; // 64^-0.25
    float out[16];
    #pragma unroll
    for (int fi = 0; fi < 16; fi++) {
        const int f = w*16 + fi;
        float d0; DOTROW64(d0, pf, ORF + (size_t)f*64);
        d0 *= norm;
        d0 = (d0 > 0.f) ? d0 : 0.f;
        out[fi] = d0 + 0.001f;
    }
    float4* pp = (float4*)(PHI + ((size_t)bh*SS + s)*FF + w*16);
    #pragma unroll
    for (int j = 0; j < 4; j++)
        pp[j] = make_float4(out[4*j], out[4*j+1], out[4*j+2], out[4*j+3]);
}

// ---------------- Kernel B1: per-chunk sums ----------------
// grid = 256 (bh*16+c), 128 threads (2 waves split s). lane = f.
__global__ __launch_bounds__(128) void kchunksum(
    const float* __restrict__ PHI_K, const float* __restrict__ VP,
    float* __restrict__ CS, float* __restrict__ KCS)
{
    __shared__ float buf[64*66 + 64];
    const int tid = threadIdx.x;
    const int l = tid & 63;
    const int w = __builtin_amdgcn_readfirstlane(tid >> 6); // 0 or 1
    const int bid = blockIdx.x;
    const size_t base = (size_t)bid * 4096;

    float accd[64];
    #pragma unroll
    for (int d = 0; d < 64; d++) accd[d] = 0.f;
    float ks = 0.f;

    #pragma unroll 2
    for (int si = 0; si < 32; si++) {
        const int srow = w*32 + si;
        float kv = PHI_K[base + (size_t)srow*64 + l];   // coalesced
        ks += kv;
        AXPYROW64(accd, kv, VP + base + (size_t)srow*64);  // uniform row
    }

    if (w == 1) {
        #pragma unroll
        for (int m = 0; m < 32; m++)
            *(float2*)&buf[l*66 + 2*m] = make_float2(accd[2*m], accd[2*m+1]);
        buf[64*66 + l] = ks;
    }
    __syncthreads();
    if (w == 0) {
        float4* cp = (float4*)(CS + base + (size_t)l*64);
        #pragma unroll
        for (int m = 0; m < 16; m++) {
            float2 t0 = *(float2*)&buf[l*66 + 4*m];
            float2 t1 = *(float2*)&buf[l*66 + 4*m + 2];
            cp[m] = make_float4(accd[4*m] + t0.x, accd[4*m+1] + t0.y,
                                accd[4*m+2] + t1.x, accd[4*m+3] + t1.y);
        }
        KCS[(size_t)bid*64 + l] = ks + buf[64*66 + l];
    }
}

// ---------------- Kernel B2: exclusive prefix over 16 chunks ----------------
// grid = 64 (bh*4+quarter), 256 threads, float4 elements.
__global__ __launch_bounds__(256) void kprefix(float* __restrict__ CS, float* __restrict__ KCS)
{
    const int tid = threadIdx.x, bid = blockIdx.x;
    const int bh = bid >> 2, q = bid & 3;
    float4 run = make_float4(0.f, 0.f, 0.f, 0.f);
    const int e4 = q*256 + tid; // 0..1023 float4 slots per 4096-float tile
    for (int c = 0; c < NCH; c++) {
        float4* p = (float4*)(CS + ((size_t)(bh*NCH + c))*4096) + e4;
        float4 t = *p; *p = run;
        run.x += t.x; run.y += t.y; run.z += t.z; run.w += t.w;
    }
    if (q == 0 && tid < 64) {
        float r = 0.f;
        for (int c = 0; c < NCH; c++) {
            size_t off = ((size_t)(bh*NCH + c))*64 + tid;
            float t = KCS[off]; KCS[off] = r; r += t;
        }
    }
}

// ---------------- Kernel C: per-chunk causal attention ----------------
// grid = 256 (bh*16+c), 256 threads. lane = s (query row); wave splits t / f.
__global__ __launch_bounds__(256) void kattn(
    const float* __restrict__ PHI_Q, const float* __restrict__ PHI_K,
    const float* __restrict__ VP, const float* __restrict__ CS,
    const float* __restrict__ KCS, float* __restrict__ O)
{
    __shared__ float kct[64*66];  // [f][s] stride 66; later reused as [s][d] combine buf
    __shared__ float part[256];
    const int tid = threadIdx.x;
    const int l = tid & 63;
    const int w = __builtin_amdgcn_readfirstlane(tid >> 6);
    const int bid = blockIdx.x;
    const size_t base = (size_t)bid * 4096;

    // S1: stage phi_k transposed kct[f][s]
    {
        const int srow = tid >> 2, f0 = (tid & 3) * 16;
        const float* kp = PHI_K + base + (size_t)srow*64 + f0;
        #pragma unroll
        for (int j = 0; j < 16; j++) kct[(f0 + j)*66 + srow] = kp[j];
    }
    __syncthreads();

    // S2: per-f inclusive scan over s, seeded with exclusive chunk prefix KCS
    {
        const int f = tid >> 2, sg = tid & 3;
        float v[16];
        #pragma unroll
        for (int j = 0; j < 16; j++) v[j] = kct[f*66 + sg*16 + j];
        #pragma unroll
        for (int j = 1; j < 16; j++) v[j] += v[j-1];
        part[f*4 + sg] = v[15];
        __syncthreads();
        float offs = KCS[(size_t)bid*64 + f];
        if (sg > 0) offs += part[f*4 + 0];
        if (sg > 1) offs += part[f*4 + 1];
        if (sg > 2) offs += part[f*4 + 2];
        #pragma unroll
        for (int j = 0; j < 16; j++) kct[f*66 + sg*16 + j] = offs + v[j];
    }
    __syncthreads();

    // S3: qn[f] = phi_q[s=l][f] / kcum[f][l]
    float qn[64];
    {
        float pq[64];
        LOADROW64(pq, PHI_Q + base + (size_t)l*64);
        #pragma unroll
        for (int f = 0; f < 64; f++) qn[f] = pq[f] / kct[f*66 + l];
    }
    // this wave's 16 qn values (wave-uniform base -> branch extract)
    float qw[16];
    if (w == 0) {
        #pragma unroll
        for (int j = 0; j < 16; j++) qw[j] = qn[j];
    } else if (w == 1) {
        #pragma unroll
        for (int j = 0; j < 16; j++) qw[j] = qn[16 + j];
    } else if (w == 2) {
        #pragma unroll
        for (int j = 0; j < 16; j++) qw[j] = qn[32 + j];
    } else {
        #pragma unroll
        for (int j = 0; j < 16; j++) qw[j] = qn[48 + j];
    }

    float accd[64];
    #pragma unroll
    for (int d = 0; d < 64; d++) accd[d] = 0.f;

    // S4: intra-chunk causal; wave w handles t in [16w,16w+16)
    #pragma unroll 4
    for (int tj = 0; tj < 16; tj++) {
        const int t = w*16 + tj;
        float a; DOTROW64(a, qn, PHI_K + base + (size_t)t*64); // uniform row
        a = (t <= l) ? a : 0.f;
        AXPYROW64(accd, a, VP + base + (size_t)t*64);           // uniform row
    }

    // S5: prefix term; wave w handles f in [16w,16w+16); CS holds exclusive P
    #pragma unroll
    for (int fj = 0; fj < 16; fj++) {
        const int f = w*16 + fj;
        AXPYROW64(accd, qw[fj], CS + base + (size_t)f*64);      // uniform row
    }

    // S6: combine 4 wave-partials through LDS (serialized, deterministic)
    __syncthreads();  // all S3 reads of kct done
    if (w == 0) {
        #pragma unroll
        for (int m = 0; m < 32; m++)
            *(float2*)&kct[l*66 + 2*m] = make_float2(accd[2*m], accd[2*m+1]);
    }
    __syncthreads();
    if (w == 1) {
        #pragma unroll
        for (int m = 0; m < 32; m++) {
            float2 t = *(float2*)&kct[l*66 + 2*m];
            *(float2*)&kct[l*66 + 2*m] = make_float2(t.x + accd[2*m], t.y + accd[2*m+1]);
        }
    }
    __syncthreads();
    if (w == 2) {
        #pragma unroll
        for (int m = 0; m < 32; m++) {
            float2 t = *(float2*)&kct[l*66 + 2*m];
            *(float2*)&kct[l*66 + 2*m] = make_float2(t.x + accd[2*m], t.y + accd[2*m+1]);
        }
    }
    __syncthreads();
    if (w == 3) {
        float4* op = (float4*)(O + base + (size_t)l*64);
        #pragma unroll
        for (int m = 0; m < 16; m++) {
            float2 t0 = *(float2*)&kct[l*66 + 4*m];
            float2 t1 = *(float2*)&kct[l*66 + 4*m + 2];
            op[m] = make_float4(accd[4*m] + t0.x, accd[4*m+1] + t0.y,
                                accd[4*m+2] + t1.x, accd[4*m+3] + t1.y);
        }
    }
}

// ---------------- Kernel D: output FC ----------------
// grid = 32 rowblocks * 8 colblocks = 256 blocks, 256 threads.
// lane = row (64/block); wave = 16-output-col group; e-chunk == head.
__global__ __launch_bounds__(256) void kfc(
    const float* __restrict__ O, const float* __restrict__ Wfc,
    const float* __restrict__ bfc, float* __restrict__ out)
{
    const int tid = threadIdx.x;
    const int l = tid & 63;
    const int w = __builtin_amdgcn_readfirstlane(tid >> 6);
    const int bid = blockIdx.x;
    const int rb = bid >> 3, cb = bid & 7;
    const int r = rb*64 + l;
    const int b = r >> 10, s = r & 1023;

    float acc[16];
    #pragma unroll
    for (int oi = 0; oi < 16; oi++) acc[oi] = bfc[cb*64 + w*16 + oi];

    #pragma unroll 1
    for (int h = 0; h < 8; h++) {
        float xr[64];
        LOADROW64(xr, O + ((size_t)((b*HH + h)*SS + s))*DD);
        #pragma unroll
        for (int oi = 0; oi < 16; oi++) {
            const int o = cb*64 + w*16 + oi;
            float d0; DOTROW64(d0, xr, Wfc + (size_t)o*DM + h*64); // uniform row
            acc[oi] += d0;
        }
    }
    float4* op = (float4*)(out + ((size_t)b*SS + s)*DM + cb*64 + w*16);
    #pragma unroll
    for (int j = 0; j < 4; j++)
        op[j] = make_float4(acc[4*j], acc[4*j+1], acc[4*j+2], acc[4*j+3]);
}

extern "C" void kernel_launch(void* const* d_in, const int* in_sizes, int n_in,
                              void* d_out, int out_size, void* d_ws, size_t ws_size,
                              hipStream_t stream) {
    const float* q_in  = (const float*)d_in[0];
    const float* k_in  = (const float*)d_in[1];
    const float* v_in  = (const float*)d_in[2];
    const float* Wq    = (const float*)d_in[3];
    const float* bq    = (const float*)d_in[4];
    const float* Wk    = (const float*)d_in[5];
    const float* bk    = (const float*)d_in[6];
    const float* Wv    = (const float*)d_in[7];
    const float* bv    = (const float*)d_in[8];
    const float* orf_q = (const float*)d_in[9];
    const float* orf_k = (const float*)d_in[10];
    const float* Wfc   = (const float*)d_in[11];
    const float* bfc   = (const float*)d_in[12];

    float* ws    = (float*)d_ws;
    float* PHI_Q = ws;                 // 1048576
    float* PHI_K = ws + 1048576;       // 1048576
    float* VP    = ws + 2097152;       // 1048576
    float* CS    = ws + 3145728;       // 1048576
    float* KCS   = ws + 4194304;       // 16384
    float* O     = ws + 4210688;       // 1048576

    kproj<<<16*16*3, 256, 0, stream>>>(q_in, k_in, v_in, Wq, bq, Wk, bk, Wv, bv,
                                       orf_q, orf_k, PHI_Q, PHI_K, VP);
    kchunksum<<<256, 128, 0, stream>>>(PHI_K, VP, CS, KCS);
    kprefix<<<64, 256, 0, stream>>>(CS, KCS);
    kattn<<<256, 256, 0, stream>>>(PHI_Q, PHI_K, VP, CS, KCS, O);
    kfc<<<256, 256, 0, stream>>>(O, Wfc, bfc, (float*)d_out);
}

// Round 4
// 133.462 us; speedup vs baseline: 1.6378x; 1.6378x over previous
//
#include <hip/hip_runtime.h>

// FastAttention (Performer-style, causal) on MI355X — bf16 MFMA pipeline.
// B=2, S=1024, H=8, DEPTH=64, NFEAT=64, D_MODEL=512. fp32 in/out.
//
//  kfuse:     Mt = norm*(ORF@W) [f][d] bf16, c = norm*(ORF@b); Wv,Wfc -> bf16
//  kproj:     phi_q = relu(x@Mt^T + c)+1e-3, phi_k same, v' = v@Wv^T + bv
//             outputs: PHI_Q[s][f], PHI_K[t][f], PHI_KT[f][s], VPT[d][s] (bf16)
//  kchunksum: per 64-chunk: CST[d][f] = (phi_k^T @ v')^T, KCS[f] = col-sums (MFMA)
//  kprefix:   exclusive prefix over 16 chunks (fp32, elementwise)
//  kattn:     scan kcum, qn = phi_q/kcum; S = tril(qn@phi_k^T); O = S@v' + qn@P (MFMA)
//  kfc:       out = O@Wfc^T + bfc  (2048x512x512 MFMA)

#define BB 2
#define SS 1024
#define HH 8
#define DD 64
#define FF 64
#define DM 512
#define NCH 16

typedef __bf16 bf16_t;
typedef __attribute__((ext_vector_type(8))) __bf16 bf16x8;
typedef __attribute__((ext_vector_type(4))) __bf16 bf16x4;
typedef __attribute__((ext_vector_type(4))) float f32x4;

#define MFMA16(a,b,c) __builtin_amdgcn_mfma_f32_16x16x32_bf16((a),(b),(c),0,0,0)

// load 8 consecutive fp32 (16B-aligned) -> bf16x8
__device__ inline bf16x8 cvt_f32x8(const float* p){
    const float4* p4 = (const float4*)p;
    float4 x = p4[0], y = p4[1];
    bf16x8 r;
    r[0]=(__bf16)x.x; r[1]=(__bf16)x.y; r[2]=(__bf16)x.z; r[3]=(__bf16)x.w;
    r[4]=(__bf16)y.x; r[5]=(__bf16)y.y; r[6]=(__bf16)y.z; r[7]=(__bf16)y.w;
    return r;
}

// ---------------- kfuse: weight fusion + bf16 conversion ----------------
__global__ __launch_bounds__(256) void kfuse(
    const float* __restrict__ orf_q, const float* __restrict__ orf_k,
    const float* __restrict__ Wq, const float* __restrict__ bq,
    const float* __restrict__ Wk, const float* __restrict__ bk,
    const float* __restrict__ Wv, const float* __restrict__ Wfc,
    bf16_t* __restrict__ Mtq, bf16_t* __restrict__ Mtk,
    float* __restrict__ cq, float* __restrict__ ck,
    bf16_t* __restrict__ WvB, bf16_t* __restrict__ WfcB)
{
    const int tid = threadIdx.x, bid = blockIdx.x;
    if (bid < 2) {
        const float* ORF = bid ? orf_k : orf_q;
        const float* W   = bid ? Wk : Wq;
        const float* bb  = bid ? bk : bq;
        bf16_t* Mt = bid ? Mtk : Mtq;
        float* cc  = bid ? ck : cq;
        const float norm = 0.35355339059327373f; // 64^-0.25
        const int f = tid >> 2, d0 = (tid & 3) * 16;
        float acc[16];
        #pragma unroll
        for (int j=0;j<16;j++) acc[j]=0.f;
        float bacc = 0.f;
        for (int e=0;e<64;e++){
            float oe = ORF[f*64+e];
            const float* wr = W + e*64 + d0;
            #pragma unroll
            for (int j=0;j<16;j++) acc[j] += oe*wr[j];
            bacc += oe*bb[e];
        }
        #pragma unroll
        for (int j=0;j<16;j++) Mt[f*64+d0+j] = (__bf16)(norm*acc[j]);
        if ((tid&3)==0) cc[f] = norm*bacc;
    } else if (bid == 2) {
        for (int i=tid;i<4096;i+=256) WvB[i] = (__bf16)Wv[i];
    } else {
        const float4* W4 = (const float4*)Wfc;
        for (int i=(bid-3)*256+tid; i<65536; i+=13*256){
            float4 v = W4[i];
            bf16x4 o; o[0]=(__bf16)v.x; o[1]=(__bf16)v.y; o[2]=(__bf16)v.z; o[3]=(__bf16)v.w;
            *(bf16x4*)(WfcB + 4*i) = o;
        }
    }
}

// ---------------- kproj: fused projection + feature map (MFMA) ----------------
// grid = 16 bh * 16 stiles = 256 blocks, 256 threads (4 waves, 16 rows each).
__global__ __launch_bounds__(256) void kproj(
    const float* __restrict__ q_in, const float* __restrict__ k_in,
    const float* __restrict__ v_in,
    const bf16_t* __restrict__ Mtq, const float* __restrict__ cq,
    const bf16_t* __restrict__ Mtk, const float* __restrict__ ck,
    const bf16_t* __restrict__ WvB, const float* __restrict__ bv,
    bf16_t* __restrict__ PHI_Q, bf16_t* __restrict__ PHI_K,
    bf16_t* __restrict__ PHI_KT, bf16_t* __restrict__ VPT)
{
    __shared__ bf16_t kt[64*72];   // transpose staging, rows 144B (16B-aligned)
    const int tid = threadIdx.x;
    const int l = tid & 63;
    const int w = __builtin_amdgcn_readfirstlane(tid >> 6);
    const int qd = l >> 4, m = l & 15;
    const int bid = blockIdx.x;
    const int bh = bid >> 4, stile = bid & 15;
    const int b = bh >> 3, h = bh & 7;
    const int s0 = stile*64;
    const int sw = s0 + w*16;

    // ---- q ----
    {
        const float* xp = q_in + ((size_t)(b*SS + sw + m))*DM + h*DD;
        bf16x8 a0 = cvt_f32x8(xp + qd*8);
        bf16x8 a1 = cvt_f32x8(xp + 32 + qd*8);
        #pragma unroll
        for (int nt=0;nt<4;nt++){
            const int f = nt*16 + m;
            float cb = cq[f];
            f32x4 acc = {cb,cb,cb,cb};
            acc = MFMA16(a0, *(const bf16x8*)(Mtq + f*64 + qd*8), acc);
            acc = MFMA16(a1, *(const bf16x8*)(Mtq + f*64 + 32 + qd*8), acc);
            #pragma unroll
            for (int r=0;r<4;r++){
                float v = acc[r];
                v = (v>0.f)?v:0.f; v += 0.001f;
                PHI_Q[((size_t)bh*SS + sw + qd*4 + r)*FF + f] = (__bf16)v;
            }
        }
    }
    // ---- k ----
    {
        const float* xp = k_in + ((size_t)(b*SS + sw + m))*DM + h*DD;
        bf16x8 a0 = cvt_f32x8(xp + qd*8);
        bf16x8 a1 = cvt_f32x8(xp + 32 + qd*8);
        #pragma unroll
        for (int nt=0;nt<4;nt++){
            const int f = nt*16 + m;
            float cb = ck[f];
            f32x4 acc = {cb,cb,cb,cb};
            acc = MFMA16(a0, *(const bf16x8*)(Mtk + f*64 + qd*8), acc);
            acc = MFMA16(a1, *(const bf16x8*)(Mtk + f*64 + 32 + qd*8), acc);
            #pragma unroll
            for (int r=0;r<4;r++){
                float v = acc[r];
                v = (v>0.f)?v:0.f; v += 0.001f;
                __bf16 h16 = (__bf16)v;
                PHI_K[((size_t)bh*SS + sw + qd*4 + r)*FF + f] = h16;
                kt[f*72 + w*16 + qd*4 + r] = h16;   // [f][s_local]
            }
        }
    }
    __syncthreads();
    {   // coalesced PHI_KT store
        const int f = tid >> 2, sg = tid & 3;
        bf16x8 v0 = *(bf16x8*)&kt[f*72 + sg*16];
        bf16x8 v1 = *(bf16x8*)&kt[f*72 + sg*16 + 8];
        bf16_t* dst = PHI_KT + ((size_t)bh*64 + f)*SS + s0 + sg*16;
        *(bf16x8*)dst = v0; *(bf16x8*)(dst+8) = v1;
    }
    __syncthreads();
    // ---- v ----
    {
        const float* xp = v_in + ((size_t)(b*SS + sw + m))*DM + h*DD;
        bf16x8 a0 = cvt_f32x8(xp + qd*8);
        bf16x8 a1 = cvt_f32x8(xp + 32 + qd*8);
        #pragma unroll
        for (int nt=0;nt<4;nt++){
            const int e = nt*16 + m;
            float cb = bv[e];
            f32x4 acc = {cb,cb,cb,cb};
            acc = MFMA16(a0, *(const bf16x8*)(WvB + e*64 + qd*8), acc);
            acc = MFMA16(a1, *(const bf16x8*)(WvB + e*64 + 32 + qd*8), acc);
            #pragma unroll
            for (int r=0;r<4;r++)
                kt[e*72 + w*16 + qd*4 + r] = (__bf16)acc[r];  // [d][s_local]
        }
    }
    __syncthreads();
    {   // coalesced VPT store
        const int d = tid >> 2, sg = tid & 3;
        bf16x8 v0 = *(bf16x8*)&kt[d*72 + sg*16];
        bf16x8 v1 = *(bf16x8*)&kt[d*72 + sg*16 + 8];
        bf16_t* dst = VPT + ((size_t)bh*64 + d)*SS + s0 + sg*16;
        *(bf16x8*)dst = v0; *(bf16x8*)(dst+8) = v1;
    }
}

// ---------------- kchunksum: CST[d][f] = (phi_k^T @ v')^T per chunk ----------------
// grid = 256 (bh*16+ch), 256 threads.
__global__ __launch_bounds__(256) void kchunksum(
    const bf16_t* __restrict__ PHI_KT, const bf16_t* __restrict__ VPT,
    float* __restrict__ CST, float* __restrict__ KCS)
{
    __shared__ float dsT[64*68];
    __shared__ float part[256];
    const int tid = threadIdx.x;
    const int l = tid & 63;
    const int w = __builtin_amdgcn_readfirstlane(tid >> 6);
    const int qd = l >> 4, m = l & 15;
    const int bid = blockIdx.x;
    const int bh = bid >> 4, ch = bid & 15;
    const int cs0 = ch*64;

    const bf16_t* ka = PHI_KT + ((size_t)bh*64 + w*16 + m)*SS + cs0;
    bf16x8 a0 = *(const bf16x8*)(ka + qd*8);
    bf16x8 a1 = *(const bf16x8*)(ka + 32 + qd*8);
    #pragma unroll
    for (int nt=0;nt<4;nt++){
        const bf16_t* vb = VPT + ((size_t)bh*64 + nt*16 + m)*SS + cs0;
        f32x4 acc = {0.f,0.f,0.f,0.f};
        acc = MFMA16(a0, *(const bf16x8*)(vb + qd*8), acc);
        acc = MFMA16(a1, *(const bf16x8*)(vb + 32 + qd*8), acc);
        #pragma unroll
        for (int r=0;r<4;r++)
            dsT[(nt*16+m)*68 + w*16 + qd*4 + r] = acc[r];  // [d][f]
    }
    {   // phi_k column sums for this chunk
        const int f = tid & 63, sg = tid >> 6;
        const bf16_t* kp = PHI_KT + ((size_t)bh*64 + f)*SS + cs0 + sg*16;
        bf16x8 x0 = *(const bf16x8*)kp;
        bf16x8 x1 = *(const bf16x8*)(kp+8);
        float sm = 0.f;
        #pragma unroll
        for (int j=0;j<8;j++) sm += (float)x0[j] + (float)x1[j];
        part[sg*64 + f] = sm;
    }
    __syncthreads();
    if (tid < 64)
        KCS[(size_t)bid*64 + tid] = part[tid] + part[64+tid] + part[128+tid] + part[192+tid];
    {
        const int d = tid >> 2, F = (tid & 3) * 16;
        float* dst = CST + ((size_t)bid*64 + d)*64 + F;
        #pragma unroll
        for (int j=0;j<4;j++)
            *(float4*)(dst + 4*j) = *(float4*)&dsT[d*68 + F + 4*j];
    }
}

// ---------------- kprefix: exclusive prefix over 16 chunks ----------------
__global__ __launch_bounds__(256) void kprefix(float* __restrict__ CST, float* __restrict__ KCS)
{
    const int tid = threadIdx.x, bid = blockIdx.x;
    const int bh = bid >> 2, q = bid & 3;
    float4 run = make_float4(0.f, 0.f, 0.f, 0.f);
    const int e4 = q*256 + tid;
    for (int c = 0; c < NCH; c++) {
        float4* p = (float4*)(CST + ((size_t)(bh*NCH + c))*4096) + e4;
        float4 t = *p; *p = run;
        run.x += t.x; run.y += t.y; run.z += t.z; run.w += t.w;
    }
    if (q == 0 && tid < 64) {
        float r = 0.f;
        for (int c = 0; c < NCH; c++) {
            size_t off = ((size_t)(bh*NCH + c))*64 + tid;
            float t = KCS[off]; KCS[off] = r; r += t;
        }
    }
}

// ---------------- kattn: per-chunk causal attention (MFMA) ----------------
// grid = 256 (bh*16+ch), 256 threads.
__global__ __launch_bounds__(256) void kattn(
    const bf16_t* __restrict__ PHI_Q, const bf16_t* __restrict__ PHI_K,
    const bf16_t* __restrict__ PHI_KT, const bf16_t* __restrict__ VPT,
    const float* __restrict__ CST, const float* __restrict__ KCS,
    bf16_t* __restrict__ O)
{
    __shared__ float kct[64*67];    // [f][s] kcum
    __shared__ bf16_t qnl[64*72];   // [s][f] qn
    __shared__ bf16_t sA[64*72];    // [s][t] masked scores
    __shared__ float part[256];
    const int tid = threadIdx.x;
    const int l = tid & 63;
    const int w = __builtin_amdgcn_readfirstlane(tid >> 6);
    const int qd = l >> 4, m = l & 15;
    const int bid = blockIdx.x;
    const int bh = bid >> 4, ch = bid & 15;
    const int cs0 = ch*64;

    // S1: phi_k^T chunk -> kct fp32
    {
        const int f = tid >> 2, sg = tid & 3;
        const bf16_t* kp = PHI_KT + ((size_t)bh*64 + f)*SS + cs0 + sg*16;
        bf16x8 x0 = *(const bf16x8*)kp;
        bf16x8 x1 = *(const bf16x8*)(kp+8);
        #pragma unroll
        for (int j=0;j<8;j++){
            kct[f*67 + sg*16 + j]     = (float)x0[j];
            kct[f*67 + sg*16 + 8 + j] = (float)x1[j];
        }
    }
    __syncthreads();
    // S2: inclusive scan along s per f, seeded by exclusive chunk prefix
    {
        const int f = tid >> 2, sg = tid & 3;
        float v[16];
        #pragma unroll
        for (int j=0;j<16;j++) v[j] = kct[f*67 + sg*16 + j];
        #pragma unroll
        for (int j=1;j<16;j++) v[j] += v[j-1];
        part[f*4 + sg] = v[15];
        __syncthreads();
        float offs = KCS[(size_t)bid*64 + f];
        if (sg > 0) offs += part[f*4 + 0];
        if (sg > 1) offs += part[f*4 + 1];
        if (sg > 2) offs += part[f*4 + 2];
        #pragma unroll
        for (int j=0;j<16;j++) kct[f*67 + sg*16 + j] = offs + v[j];
    }
    __syncthreads();
    // S3: qn = phi_q / kcum -> qnl bf16 [s][f]
    {
        const int sr = tid >> 2, F = (tid & 3) * 16;
        const bf16_t* qp = PHI_Q + ((size_t)bh*SS + cs0 + sr)*FF + F;
        bf16x8 x0 = *(const bf16x8*)qp;
        bf16x8 x1 = *(const bf16x8*)(qp+8);
        bf16x8 o0, o1;
        #pragma unroll
        for (int j=0;j<8;j++){
            o0[j] = (__bf16)((float)x0[j] / kct[(F+j)*67 + sr]);
            o1[j] = (__bf16)((float)x1[j] / kct[(F+8+j)*67 + sr]);
        }
        *(bf16x8*)&qnl[sr*72 + F]     = o0;
        *(bf16x8*)&qnl[sr*72 + F + 8] = o1;
    }
    __syncthreads();

    bf16x8 qa0 = *(bf16x8*)&qnl[(w*16+m)*72 + qd*8];
    bf16x8 qa1 = *(bf16x8*)&qnl[(w*16+m)*72 + 32 + qd*8];

    // S4: S = tril(qn @ phi_k^T) -> sA bf16
    #pragma unroll
    for (int nt=0;nt<4;nt++){
        const bf16_t* kb = PHI_K + ((size_t)bh*SS + cs0 + nt*16 + m)*FF;
        f32x4 acc = {0.f,0.f,0.f,0.f};
        acc = MFMA16(qa0, *(const bf16x8*)(kb + qd*8), acc);
        acc = MFMA16(qa1, *(const bf16x8*)(kb + 32 + qd*8), acc);
        const int t_loc = nt*16 + m;
        #pragma unroll
        for (int r=0;r<4;r++){
            const int s_loc = w*16 + qd*4 + r;
            float v = (t_loc <= s_loc) ? acc[r] : 0.f;
            sA[s_loc*72 + t_loc] = (__bf16)v;
        }
    }
    __syncthreads();

    bf16x8 sa0 = *(bf16x8*)&sA[(w*16+m)*72 + qd*8];
    bf16x8 sa1 = *(bf16x8*)&sA[(w*16+m)*72 + 32 + qd*8];

    // S5: O = S@v' + qn@P
    #pragma unroll
    for (int nt=0;nt<4;nt++){
        const int d = nt*16 + m;
        const bf16_t* vb = VPT + ((size_t)bh*64 + d)*SS + cs0;
        const float* pp = CST + ((size_t)bid*64 + d)*64;
        f32x4 acc = {0.f,0.f,0.f,0.f};
        acc = MFMA16(sa0, *(const bf16x8*)(vb + qd*8), acc);
        acc = MFMA16(sa1, *(const bf16x8*)(vb + 32 + qd*8), acc);
        acc = MFMA16(qa0, cvt_f32x8(pp + qd*8), acc);
        acc = MFMA16(qa1, cvt_f32x8(pp + 32 + qd*8), acc);
        #pragma unroll
        for (int r=0;r<4;r++)
            O[((size_t)bh*SS + cs0 + w*16 + qd*4 + r)*DD + d] = (__bf16)acc[r];
    }
}

// ---------------- kfc: out = O @ Wfc^T + bfc (MFMA) ----------------
// grid = 32 rowtiles * 8 coltiles = 256 blocks, 256 threads.
__global__ __launch_bounds__(256) void kfc(
    const bf16_t* __restrict__ O, const bf16_t* __restrict__ WfcB,
    const float* __restrict__ bfc, float* __restrict__ out)
{
    const int tid = threadIdx.x;
    const int l = tid & 63;
    const int w = __builtin_amdgcn_readfirstlane(tid >> 6);
    const int qd = l >> 4, m = l & 15;
    const int bid = blockIdx.x;
    const int rb = bid >> 3, cb = bid & 7;
    const int r0 = rb*64 + w*16;

    f32x4 acc[4];
    #pragma unroll
    for (int nt=0;nt<4;nt++){
        float bb = bfc[cb*64 + nt*16 + m];
        acc[nt][0]=bb; acc[nt][1]=bb; acc[nt][2]=bb; acc[nt][3]=bb;
    }
    const int row = r0 + m;
    const int b = row >> 10, s = row & 1023;
    #pragma unroll 2
    for (int c=0;c<16;c++){
        const int h = c >> 1;
        const int doff = (c & 1)*32 + qd*8;
        bf16x8 a = *(const bf16x8*)(O + ((size_t)((b*HH + h)*SS + s))*DD + doff);
        #pragma unroll
        for (int nt=0;nt<4;nt++){
            bf16x8 bfr = *(const bf16x8*)(WfcB + (size_t)(cb*64 + nt*16 + m)*DM + c*32 + qd*8);
            acc[nt] = MFMA16(a, bfr, acc[nt]);
        }
    }
    #pragma unroll
    for (int nt=0;nt<4;nt++){
        #pragma unroll
        for (int r=0;r<4;r++){
            const int rr = r0 + qd*4 + r;
            out[(size_t)rr*DM + cb*64 + nt*16 + m] = acc[nt][r];
        }
    }
}

extern "C" void kernel_launch(void* const* d_in, const int* in_sizes, int n_in,
                              void* d_out, int out_size, void* d_ws, size_t ws_size,
                              hipStream_t stream) {
    const float* q_in  = (const float*)d_in[0];
    const float* k_in  = (const float*)d_in[1];
    const float* v_in  = (const float*)d_in[2];
    const float* Wq    = (const float*)d_in[3];
    const float* bq    = (const float*)d_in[4];
    const float* Wk    = (const float*)d_in[5];
    const float* bk    = (const float*)d_in[6];
    const float* Wv    = (const float*)d_in[7];
    const float* bv    = (const float*)d_in[8];
    const float* orf_q = (const float*)d_in[9];
    const float* orf_k = (const float*)d_in[10];
    const float* Wfc   = (const float*)d_in[11];
    const float* bfc   = (const float*)d_in[12];

    float* CST   = (float*)d_ws;                 // 256*4096 fp32 = 4 MB
    float* KCS   = CST + 1048576;                // 16384 fp32
    bf16_t* PHI_Q  = (bf16_t*)(KCS + 16384);     // 1M bf16
    bf16_t* PHI_K  = PHI_Q + 1048576;
    bf16_t* PHI_KT = PHI_K + 1048576;
    bf16_t* VPT    = PHI_KT + 1048576;
    bf16_t* O      = VPT + 1048576;
    bf16_t* Mtq    = O + 1048576;                // 4096
    bf16_t* Mtk    = Mtq + 4096;
    bf16_t* WvB    = Mtk + 4096;
    bf16_t* WfcB   = WvB + 4096;                 // 262144
    float* cq      = (float*)(WfcB + 262144);
    float* ck      = cq + 64;

    kfuse<<<16, 256, 0, stream>>>(orf_q, orf_k, Wq, bq, Wk, bk, Wv, Wfc,
                                  Mtq, Mtk, cq, ck, WvB, WfcB);
    kproj<<<256, 256, 0, stream>>>(q_in, k_in, v_in, Mtq, cq, Mtk, ck, WvB, bv,
                                   PHI_Q, PHI_K, PHI_KT, VPT);
    kchunksum<<<256, 256, 0, stream>>>(PHI_KT, VPT, CST, KCS);
    kprefix<<<64, 256, 0, stream>>>(CST, KCS);
    kattn<<<256, 256, 0, stream>>>(PHI_Q, PHI_K, PHI_KT, VPT, CST, KCS, O);
    kfc<<<256, 256, 0, stream>>>(O, WfcB, bfc, (float*)d_out);
}